// Round 11
// baseline (175.781 us; speedup 1.0000x reference)
//
#include <hip/hip_runtime.h>
#include <hip/hip_bf16.h>
#include <cstdint>

#define N_NODES 50000
#define N_EDGES 800000
#define D 96
#define NEG_SLOPE 0.2f
#define R1ROWS 16    // 50000 = 3125 * 16 exactly -> no tail guards
#define BUCKET 64    // max in-degree slack: Poisson(16) tail past 64 ~ 1e-19/node
#define NXCD 8
#define DST_PER_PART (N_NODES / NXCD)   // 6250 exactly

// K1: LDS GEMM fused with attention dots. 16 rows/block, block (96,4)=384.
// Stores bf16 h only; a_src/a_dst via 32-slot LDS-atomic reduction (one
// address per bank); zeroes cnt (replaces memset + the old k1b kernel).
__global__ __launch_bounds__(384) void k1_gemm(
    const float* __restrict__ x, const float* __restrict__ W,
    const float* __restrict__ att_src, const float* __restrict__ att_dst,
    __hip_bfloat16* __restrict__ hb, float* __restrict__ a_src,
    float* __restrict__ a_dst, int* __restrict__ cnt) {
    __shared__ float Ws[D][D];      // [k][col] — native W layout
    __shared__ float xs[R1ROWS][D]; // [row][k]
    __shared__ float rs[R1ROWS];    // a_src partials (banks 0..15)
    __shared__ float rd[R1ROWS];    // a_dst partials (banks 16..31)
    const int tx = threadIdx.x, ty = threadIdx.y;
    const int t = ty * 96 + tx;     // 0..383
    const size_t row0 = (size_t)blockIdx.x * R1ROWS;

    {   // stage W (2304 float4) and x tile (384 float4), fully coalesced
        const float4* W4 = (const float4*)W;
        float4* Ws4 = (float4*)Ws;
#pragma unroll
        for (int i = 0; i < 6; ++i) Ws4[t + 384 * i] = W4[t + 384 * i];
        const float4* x4 = (const float4*)(x + row0 * D);
        ((float4*)xs)[t] = x4[t];
    }
    if (t < R1ROWS) { rs[t] = 0.f; rd[t] = 0.f; }
    __syncthreads();

    float acc0 = 0.f, acc1 = 0.f, acc2 = 0.f, acc3 = 0.f;
#pragma unroll
    for (int k = 0; k < D; k += 4) {
        float4 xa = *(const float4*)&xs[ty][k];
        float4 xb = *(const float4*)&xs[ty + 4][k];
        float4 xc = *(const float4*)&xs[ty + 8][k];
        float4 xd = *(const float4*)&xs[ty + 12][k];
        float w0 = Ws[k][tx], w1 = Ws[k + 1][tx], w2 = Ws[k + 2][tx], w3 = Ws[k + 3][tx];
        acc0 += xa.x * w0 + xa.y * w1 + xa.z * w2 + xa.w * w3;
        acc1 += xb.x * w0 + xb.y * w1 + xb.z * w2 + xb.w * w3;
        acc2 += xc.x * w0 + xc.y * w1 + xc.z * w2 + xc.w * w3;
        acc3 += xd.x * w0 + xd.y * w1 + xd.z * w2 + xd.w * w3;
    }
    hb[(row0 + ty     ) * D + tx] = __float2bfloat16(acc0);
    hb[(row0 + ty + 4 ) * D + tx] = __float2bfloat16(acc1);
    hb[(row0 + ty + 8 ) * D + tx] = __float2bfloat16(acc2);
    hb[(row0 + ty + 12) * D + tx] = __float2bfloat16(acc3);

    const float as = att_src[tx];
    const float ad = att_dst[tx];
    atomicAdd(&rs[ty],      acc0 * as);
    atomicAdd(&rs[ty + 4],  acc1 * as);
    atomicAdd(&rs[ty + 8],  acc2 * as);
    atomicAdd(&rs[ty + 12], acc3 * as);
    atomicAdd(&rd[ty],      acc0 * ad);
    atomicAdd(&rd[ty + 4],  acc1 * ad);
    atomicAdd(&rd[ty + 8],  acc2 * ad);
    atomicAdd(&rd[ty + 12], acc3 * ad);
    __syncthreads();
    if (t < R1ROWS) {
        a_src[row0 + t] = rs[t];
        a_dst[row0 + t] = rd[t];
        cnt[row0 + t] = 0;
    }
}

// Single-pass CSR-bucket build, XCD-partitioned by dst range.
// blockIdx&7 selects the dst partition (round-robin XCD placement premise);
// blockIdx>>3 selects the edge chunk. Each edge is read by 8 blocks,
// processed by exactly one — so each bucket/cnt line is written by ONE XCD.
__global__ void k_bucket(const int* __restrict__ ei,
                         const float* __restrict__ a_src, const float* __restrict__ a_dst,
                         int* __restrict__ cnt, uint* __restrict__ bkt) {
    const int part = blockIdx.x & (NXCD - 1);
    const int e = (blockIdx.x >> 3) * 256 + threadIdx.x;
    if (e >= N_EDGES) return;
    int d = ei[N_EDGES + e];
    int lo = part * DST_PER_PART;
    if (d < lo || d >= lo + DST_PER_PART) return;
    int s = ei[e];
    float v = a_src[s] + a_dst[d];
    v = v > 0.f ? v : NEG_SLOPE * v;
    float w = __expf(v);
    uint u = __float_as_uint(w);
    uint wb = (u + 0x7FFFu + ((u >> 16) & 1u)) & 0xFFFF0000u;  // RNE bf16, kept in high half
    uint pk = wb | (uint)s;                                    // src < 65536
    int pos = atomicAdd(&cnt[d], 1);
    if (pos < BUCKET) bkt[(size_t)d * BUCKET + pos] = pk;
}

// One WAVE per node, zero barriers. Lanes 0..47 each own 2 features (one
// bf16x2 = 4B load per edge). Bucket entries read 8-at-a-time via two uint4
// loads -> 8 independent gather chains in flight. 24-bit index math.
__global__ __launch_bounds__(256) void k_gather(
    const int* __restrict__ cnt, const uint* __restrict__ bkt,
    const float* __restrict__ a_src, const float* __restrict__ a_dst,
    const __hip_bfloat16* __restrict__ hb, const float* __restrict__ bias,
    float* __restrict__ out) {
    const uint lane = threadIdx.x & 63;
    const int node = (blockIdx.x * 256 + threadIdx.x) >> 6;
    if (node >= N_NODES) return;
    const uint* __restrict__ hbu = (const uint*)hb;  // one uint = 2 bf16 features
    const uint* __restrict__ bucket = bkt + (size_t)node * BUCKET;
    const int cn = min(cnt[node], BUCKET);

    // self-loop
    float es = a_src[node] + a_dst[node];
    es = es > 0.f ? es : NEG_SLOPE * es;
    float wself = __expf(es);
    uint pself = hbu[(uint)node * 48u + lane];  // lanes>=48 read garbage, unused
    float acc0 = __uint_as_float(pself << 16) * wself;
    float acc1 = __uint_as_float(pself & 0xffff0000u) * wself;
    float wsum = wself;

    int k = 0;
    for (; k + 7 < cn; k += 8) {
        uint4 b0 = *(const uint4*)&bucket[k];
        uint4 b1 = *(const uint4*)&bucket[k + 4];
        uint p0 = hbu[(b0.x & 0xFFFFu) * 48u + lane];
        uint p1 = hbu[(b0.y & 0xFFFFu) * 48u + lane];
        uint p2 = hbu[(b0.z & 0xFFFFu) * 48u + lane];
        uint p3 = hbu[(b0.w & 0xFFFFu) * 48u + lane];
        uint p4 = hbu[(b1.x & 0xFFFFu) * 48u + lane];
        uint p5 = hbu[(b1.y & 0xFFFFu) * 48u + lane];
        uint p6 = hbu[(b1.z & 0xFFFFu) * 48u + lane];
        uint p7 = hbu[(b1.w & 0xFFFFu) * 48u + lane];
        float w0 = __uint_as_float(b0.x & 0xFFFF0000u);
        float w1 = __uint_as_float(b0.y & 0xFFFF0000u);
        float w2 = __uint_as_float(b0.z & 0xFFFF0000u);
        float w3 = __uint_as_float(b0.w & 0xFFFF0000u);
        float w4 = __uint_as_float(b1.x & 0xFFFF0000u);
        float w5 = __uint_as_float(b1.y & 0xFFFF0000u);
        float w6 = __uint_as_float(b1.z & 0xFFFF0000u);
        float w7 = __uint_as_float(b1.w & 0xFFFF0000u);
        acc0 += __uint_as_float(p0 << 16) * w0 + __uint_as_float(p1 << 16) * w1
              + __uint_as_float(p2 << 16) * w2 + __uint_as_float(p3 << 16) * w3
              + __uint_as_float(p4 << 16) * w4 + __uint_as_float(p5 << 16) * w5
              + __uint_as_float(p6 << 16) * w6 + __uint_as_float(p7 << 16) * w7;
        acc1 += __uint_as_float(p0 & 0xffff0000u) * w0 + __uint_as_float(p1 & 0xffff0000u) * w1
              + __uint_as_float(p2 & 0xffff0000u) * w2 + __uint_as_float(p3 & 0xffff0000u) * w3
              + __uint_as_float(p4 & 0xffff0000u) * w4 + __uint_as_float(p5 & 0xffff0000u) * w5
              + __uint_as_float(p6 & 0xffff0000u) * w6 + __uint_as_float(p7 & 0xffff0000u) * w7;
        wsum += ((w0 + w1) + (w2 + w3)) + ((w4 + w5) + (w6 + w7));
    }
    if (k + 3 < cn) {
        uint4 b0 = *(const uint4*)&bucket[k];
        uint p0 = hbu[(b0.x & 0xFFFFu) * 48u + lane];
        uint p1 = hbu[(b0.y & 0xFFFFu) * 48u + lane];
        uint p2 = hbu[(b0.z & 0xFFFFu) * 48u + lane];
        uint p3 = hbu[(b0.w & 0xFFFFu) * 48u + lane];
        float w0 = __uint_as_float(b0.x & 0xFFFF0000u);
        float w1 = __uint_as_float(b0.y & 0xFFFF0000u);
        float w2 = __uint_as_float(b0.z & 0xFFFF0000u);
        float w3 = __uint_as_float(b0.w & 0xFFFF0000u);
        acc0 += __uint_as_float(p0 << 16) * w0 + __uint_as_float(p1 << 16) * w1
              + __uint_as_float(p2 << 16) * w2 + __uint_as_float(p3 << 16) * w3;
        acc1 += __uint_as_float(p0 & 0xffff0000u) * w0 + __uint_as_float(p1 & 0xffff0000u) * w1
              + __uint_as_float(p2 & 0xffff0000u) * w2 + __uint_as_float(p3 & 0xffff0000u) * w3;
        wsum += (w0 + w1) + (w2 + w3);
        k += 4;
    }
    for (; k < cn; ++k) {
        uint e0 = bucket[k];
        uint p0 = hbu[(e0 & 0xFFFFu) * 48u + lane];
        float w0 = __uint_as_float(e0 & 0xFFFF0000u);
        acc0 += __uint_as_float(p0 << 16) * w0;
        acc1 += __uint_as_float(p0 & 0xffff0000u) * w0;
        wsum += w0;
    }

    if (lane < 48) {
        float inv = 1.f / (wsum + 1e-16f);
        float2 bv = *(const float2*)(bias + lane * 2);
        float2 o;
        o.x = tanhf(acc0 * inv + bv.x);
        o.y = tanhf(acc1 * inv + bv.y);
        *(float2*)(out + (size_t)node * D + lane * 2) = o;
    }
}

extern "C" void kernel_launch(void* const* d_in, const int* in_sizes, int n_in,
                              void* d_out, int out_size, void* d_ws, size_t ws_size,
                              hipStream_t stream) {
    const float* x       = (const float*)d_in[0];
    const float* W       = (const float*)d_in[1];
    const float* att_src = (const float*)d_in[2];
    const float* att_dst = (const float*)d_in[3];
    const float* bias    = (const float*)d_in[4];
    const int*   ei      = (const int*)d_in[5];
    float* out = (float*)d_out;

    char* ws = (char*)d_ws;
    __hip_bfloat16* hb = (__hip_bfloat16*)ws; ws += (size_t)N_NODES * D * 2;
    float* a_src  = (float*)ws; ws += (size_t)N_NODES * 4;
    float* a_dst  = (float*)ws; ws += (size_t)N_NODES * 4;
    int*   cnt    = (int*)ws;   ws += (size_t)N_NODES * 4;
    uint*  bkt    = (uint*)ws;  ws += (size_t)N_NODES * BUCKET * 4;

    k1_gemm<<<N_NODES / R1ROWS, dim3(96, 4), 0, stream>>>(
        x, W, att_src, att_dst, hb, a_src, a_dst, cnt);
    k_bucket<<<((N_EDGES + 255) / 256) * NXCD, 256, 0, stream>>>(ei, a_src, a_dst, cnt, bkt);
    k_gather<<<(N_NODES * 64 + 255) / 256, 256, 0, stream>>>(cnt, bkt, a_src, a_dst, hb, bias, out);
}

// Round 12
// 120.585 us; speedup vs baseline: 1.4577x; 1.4577x over previous
//
#include <hip/hip_runtime.h>
#include <hip/hip_bf16.h>
#include <cstdint>

#define N_NODES 50000
#define N_EDGES 800000
#define D 96
#define NEG_SLOPE 0.2f
#define R1ROWS 16    // 50000 = 3125 * 16 exactly -> no tail guards
#define BUCKET 64    // max in-degree slack: Poisson(16) tail past 64 ~ 1e-19/node
#define NXCD 8
#define DST_PER_PART (N_NODES / NXCD)   // 6250 exactly

// K0: p_src = W @ att_src, p_dst = W @ att_dst  (96-vectors). One block.
// Enables a_src[i] = x[i]·p_src without needing f32 h anywhere.
__global__ __launch_bounds__(384) void k0_proj(
    const float* __restrict__ W, const float* __restrict__ att_src,
    const float* __restrict__ att_dst, float* __restrict__ p_src,
    float* __restrict__ p_dst) {
    __shared__ float Wl[D * (D + 1)];   // padded rows: bank-conflict-free row reads
    __shared__ float asl[D], adl[D];
    __shared__ float rs[4][D], rd[4][D];
    const int tx = threadIdx.x, ty = threadIdx.y;
    const int t = ty * 96 + tx;
    for (int i = t; i < D * D; i += 384) Wl[(i / D) * (D + 1) + (i % D)] = W[i];
    if (t < D) { asl[t] = att_src[t]; adl[t] = att_dst[t]; }
    __syncthreads();
    float ps = 0.f, pd = 0.f;
    const float* wrow = &Wl[tx * (D + 1) + ty * 24];
#pragma unroll
    for (int c = 0; c < 24; ++c) {
        float w = wrow[c];
        ps += w * asl[ty * 24 + c];
        pd += w * adl[ty * 24 + c];
    }
    rs[ty][tx] = ps; rd[ty][tx] = pd;
    __syncthreads();
    if (ty == 0) {
        p_src[tx] = rs[0][tx] + rs[1][tx] + rs[2][tx] + rs[3][tx];
        p_dst[tx] = rd[0][tx] + rd[1][tx] + rd[2][tx] + rd[3][tx];
    }
}

// K1: LDS GEMM, 16 rows/block, block (96,4)=384 threads. Stores bf16 h ONLY.
__global__ __launch_bounds__(384) void k1_gemm(
    const float* __restrict__ x, const float* __restrict__ W,
    __hip_bfloat16* __restrict__ hb) {
    __shared__ float Ws[D][D];      // [k][col] — native W layout
    __shared__ float xs[R1ROWS][D]; // [row][k]
    const int tx = threadIdx.x, ty = threadIdx.y;
    const int t = ty * 96 + tx;     // 0..383
    const size_t row0 = (size_t)blockIdx.x * R1ROWS;

    {   // stage W (2304 float4) and x tile (384 float4), fully coalesced
        const float4* W4 = (const float4*)W;
        float4* Ws4 = (float4*)Ws;
#pragma unroll
        for (int i = 0; i < 6; ++i) Ws4[t + 384 * i] = W4[t + 384 * i];
        const float4* x4 = (const float4*)(x + row0 * D);
        ((float4*)xs)[t] = x4[t];
    }
    __syncthreads();

    float acc0 = 0.f, acc1 = 0.f, acc2 = 0.f, acc3 = 0.f;
#pragma unroll
    for (int k = 0; k < D; k += 4) {
        float4 xa = *(const float4*)&xs[ty][k];
        float4 xb = *(const float4*)&xs[ty + 4][k];
        float4 xc = *(const float4*)&xs[ty + 8][k];
        float4 xd = *(const float4*)&xs[ty + 12][k];
        float w0 = Ws[k][tx], w1 = Ws[k + 1][tx], w2 = Ws[k + 2][tx], w3 = Ws[k + 3][tx];
        acc0 += xa.x * w0 + xa.y * w1 + xa.z * w2 + xa.w * w3;
        acc1 += xb.x * w0 + xb.y * w1 + xb.z * w2 + xb.w * w3;
        acc2 += xc.x * w0 + xc.y * w1 + xc.z * w2 + xc.w * w3;
        acc3 += xd.x * w0 + xd.y * w1 + xd.z * w2 + xd.w * w3;
    }
    hb[(row0 + ty     ) * D + tx] = __float2bfloat16(acc0);
    hb[(row0 + ty + 4 ) * D + tx] = __float2bfloat16(acc1);
    hb[(row0 + ty + 8 ) * D + tx] = __float2bfloat16(acc2);
    hb[(row0 + ty + 12) * D + tx] = __float2bfloat16(acc3);
}

// K1b: a_src[i] = x[i]·p_src, a_dst[i] = x[i]·p_dst — one wave per row,
// lanes 0..47 hold float2, shuffle-reduce. Also zeroes cnt[row].
__global__ __launch_bounds__(256) void k1b_att(
    const float* __restrict__ x, const float* __restrict__ p_src,
    const float* __restrict__ p_dst, float* __restrict__ a_src,
    float* __restrict__ a_dst, int* __restrict__ cnt) {
    const int lane = threadIdx.x & 63;
    const int row = (blockIdx.x * 256 + threadIdx.x) >> 6;
    if (row >= N_NODES) return;
    float s = 0.f, d = 0.f;
    if (lane < 48) {
        float2 xv = *(const float2*)(x + (size_t)row * D + lane * 2);
        float2 ps = *(const float2*)(p_src + lane * 2);
        float2 pd = *(const float2*)(p_dst + lane * 2);
        s = xv.x * ps.x + xv.y * ps.y;
        d = xv.x * pd.x + xv.y * pd.y;
    }
#pragma unroll
    for (int off = 32; off >= 1; off >>= 1) {
        s += __shfl_down(s, off);
        d += __shfl_down(d, off);
    }
    if (lane == 0) { a_src[row] = s; a_dst[row] = d; cnt[row] = 0; }
}

// Single-pass CSR-bucket build, XCD-partitioned by dst range.
// blockIdx&7 selects the dst partition; blockIdx>>3 the edge chunk. Each
// edge is read by 8 blocks, processed by one — each bucket/cnt line is
// written from ONE XCD (kills cross-XCD line ping-pong).
__global__ void k_bucket(const int* __restrict__ ei,
                         const float* __restrict__ a_src, const float* __restrict__ a_dst,
                         int* __restrict__ cnt, uint* __restrict__ bkt) {
    const int part = blockIdx.x & (NXCD - 1);
    const int e = (blockIdx.x >> 3) * 256 + threadIdx.x;
    if (e >= N_EDGES) return;
    int d = ei[N_EDGES + e];
    int lo = part * DST_PER_PART;
    if (d < lo || d >= lo + DST_PER_PART) return;
    int s = ei[e];
    float v = a_src[s] + a_dst[d];
    v = v > 0.f ? v : NEG_SLOPE * v;
    float w = __expf(v);
    uint u = __float_as_uint(w);
    uint wb = (u + 0x7FFFu + ((u >> 16) & 1u)) & 0xFFFF0000u;  // RNE bf16, kept in high half
    uint pk = wb | (uint)s;                                    // src < 65536
    int pos = atomicAdd(&cnt[d], 1);
    if (pos < BUCKET) bkt[(size_t)d * BUCKET + pos] = pk;
}

// One WAVE per node, zero barriers. Lanes 0..47 each own 2 features (one
// bf16x2 = 4B load per edge). Main loop: 16 bucket entries via four uint4
// loads -> 16 independent gather chains in flight (avg degree 16 -> one
// latency round for most nodes). 24-bit index math.
__global__ __launch_bounds__(256) void k_gather(
    const int* __restrict__ cnt, const uint* __restrict__ bkt,
    const float* __restrict__ a_src, const float* __restrict__ a_dst,
    const __hip_bfloat16* __restrict__ hb, const float* __restrict__ bias,
    float* __restrict__ out) {
    const uint lane = threadIdx.x & 63;
    const int node = (blockIdx.x * 256 + threadIdx.x) >> 6;
    if (node >= N_NODES) return;
    const uint* __restrict__ hbu = (const uint*)hb;  // one uint = 2 bf16 features
    const uint* __restrict__ bucket = bkt + (size_t)node * BUCKET;
    const int cn = min(cnt[node], BUCKET);

    // self-loop
    float es = a_src[node] + a_dst[node];
    es = es > 0.f ? es : NEG_SLOPE * es;
    float wself = __expf(es);
    uint pself = hbu[(uint)node * 48u + lane];  // lanes>=48 read garbage, unused
    float acc0 = __uint_as_float(pself << 16) * wself;
    float acc1 = __uint_as_float(pself & 0xffff0000u) * wself;
    float wsum = wself;

    int k = 0;
    for (; k + 15 < cn; k += 16) {
        uint b[16];
        *(uint4*)&b[0]  = *(const uint4*)&bucket[k];
        *(uint4*)&b[4]  = *(const uint4*)&bucket[k + 4];
        *(uint4*)&b[8]  = *(const uint4*)&bucket[k + 8];
        *(uint4*)&b[12] = *(const uint4*)&bucket[k + 12];
        uint p[16];
#pragma unroll
        for (int j = 0; j < 16; ++j) p[j] = hbu[(b[j] & 0xFFFFu) * 48u + lane];
#pragma unroll
        for (int j = 0; j < 16; ++j) {
            float w = __uint_as_float(b[j] & 0xFFFF0000u);
            acc0 += __uint_as_float(p[j] << 16) * w;
            acc1 += __uint_as_float(p[j] & 0xffff0000u) * w;
            wsum += w;
        }
    }
    if (k + 7 < cn) {
        uint b[8];
        *(uint4*)&b[0] = *(const uint4*)&bucket[k];
        *(uint4*)&b[4] = *(const uint4*)&bucket[k + 4];
        uint p[8];
#pragma unroll
        for (int j = 0; j < 8; ++j) p[j] = hbu[(b[j] & 0xFFFFu) * 48u + lane];
#pragma unroll
        for (int j = 0; j < 8; ++j) {
            float w = __uint_as_float(b[j] & 0xFFFF0000u);
            acc0 += __uint_as_float(p[j] << 16) * w;
            acc1 += __uint_as_float(p[j] & 0xffff0000u) * w;
            wsum += w;
        }
        k += 8;
    }
    if (k + 3 < cn) {
        uint b[4];
        *(uint4*)&b[0] = *(const uint4*)&bucket[k];
        uint p[4];
#pragma unroll
        for (int j = 0; j < 4; ++j) p[j] = hbu[(b[j] & 0xFFFFu) * 48u + lane];
#pragma unroll
        for (int j = 0; j < 4; ++j) {
            float w = __uint_as_float(b[j] & 0xFFFF0000u);
            acc0 += __uint_as_float(p[j] << 16) * w;
            acc1 += __uint_as_float(p[j] & 0xffff0000u) * w;
            wsum += w;
        }
        k += 4;
    }
    for (; k < cn; ++k) {
        uint e0 = bucket[k];
        uint p0 = hbu[(e0 & 0xFFFFu) * 48u + lane];
        float w0 = __uint_as_float(e0 & 0xFFFF0000u);
        acc0 += __uint_as_float(p0 << 16) * w0;
        acc1 += __uint_as_float(p0 & 0xffff0000u) * w0;
        wsum += w0;
    }

    if (lane < 48) {
        float inv = 1.f / (wsum + 1e-16f);
        float2 bv = *(const float2*)(bias + lane * 2);
        float2 o;
        o.x = tanhf(acc0 * inv + bv.x);
        o.y = tanhf(acc1 * inv + bv.y);
        *(float2*)(out + (size_t)node * D + lane * 2) = o;
    }
}

extern "C" void kernel_launch(void* const* d_in, const int* in_sizes, int n_in,
                              void* d_out, int out_size, void* d_ws, size_t ws_size,
                              hipStream_t stream) {
    const float* x       = (const float*)d_in[0];
    const float* W       = (const float*)d_in[1];
    const float* att_src = (const float*)d_in[2];
    const float* att_dst = (const float*)d_in[3];
    const float* bias    = (const float*)d_in[4];
    const int*   ei      = (const int*)d_in[5];
    float* out = (float*)d_out;

    char* ws = (char*)d_ws;
    __hip_bfloat16* hb = (__hip_bfloat16*)ws; ws += (size_t)N_NODES * D * 2;
    float* a_src  = (float*)ws; ws += (size_t)N_NODES * 4;
    float* a_dst  = (float*)ws; ws += (size_t)N_NODES * 4;
    int*   cnt    = (int*)ws;   ws += (size_t)N_NODES * 4;
    float* p_src  = (float*)ws; ws += (size_t)D * 4;
    float* p_dst  = (float*)ws; ws += (size_t)D * 4;
    uint*  bkt    = (uint*)ws;  ws += (size_t)N_NODES * BUCKET * 4;

    k0_proj<<<1, dim3(96, 4), 0, stream>>>(W, att_src, att_dst, p_src, p_dst);
    k1b_att<<<(N_NODES * 64 + 255) / 256, 256, 0, stream>>>(x, p_src, p_dst, a_src, a_dst, cnt);
    k_bucket<<<((N_EDGES + 255) / 256) * NXCD, 256, 0, stream>>>(ei, a_src, a_dst, cnt, bkt);
    k1_gemm<<<N_NODES / R1ROWS, dim3(96, 4), 0, stream>>>(x, W, hb);
    k_gather<<<(N_NODES * 64 + 255) / 256, 256, 0, stream>>>(cnt, bkt, a_src, a_dst, hb, bias, out);
}